// Round 2
// baseline (22388.510 us; speedup 1.0000x reference)
//
#include <hip/hip_runtime.h>
#include <hip/hip_bf16.h>

#define Bdim 128
#define Tdim 256
#define DIN 512
#define Hdim 1024
#define Sdim 128
#define DHdim 1024
#define KG 1152   // S + H (gates GEMM K)
#define KP 1536   // DIN + H (heads GEMM K)
#define NBLK 192  // persistent: 128 gates blocks + 64 heads blocks

using short8  = __attribute__((ext_vector_type(8))) short;   // 8 bf16 (4 VGPRs)
using floatx4 = __attribute__((ext_vector_type(4))) float;   // MFMA accum

#define MFMA(a, b, c) __builtin_amdgcn_mfma_f32_16x16x32_bf16((a), (b), (c), 0, 0, 0)

// ---- workspace layout (bytes). Scan-phase staging (xbf/Wg/Wmv) unions with
// Hbuf (decoder intermediate), which is written only after the scan finishes.
#define XBF_OFF   0ull            // 128*256*512 bf16 = 33,554,432
#define WG_OFF    33554432ull     // 4096*1152 bf16 = 9,437,184
#define WMV_OFF   42991616ull     // 256*1536 bf16 = 786,432
#define HB_OFF    0ull            // 32768*1024 bf16 = 67,108,864 (unions scan staging)
#define WD1_OFF   67108864ull     // 1024*128 bf16 = 262,144
#define WD2_OFF   67371008ull     // 512*1024 bf16 = 1,048,576
#define AB_OFF    68419584ull     // 2 x 128*1152 bf16 (ping-pong [z|h]) = 589,824
#define AB_SZ     294912ull
#define ZALL_OFF  69009408ull     // 32768*128 bf16 = 8,388,608
#define KL_OFF    77398016ull     // 1 f32
#define BAR_OFF   77398144ull     // cnt @+0, gen @+128

__device__ __forceinline__ float sigf(float v) { return 1.0f / (1.0f + __expf(-v)); }
__device__ __forceinline__ float tanhfast(float v) { return 1.0f - 2.0f / (__expf(2.0f * v) + 1.0f); }

// ---------------- prep: fp32->bf16 conversions, weight packing, state zeroing
__global__ __launch_bounds__(256) void prep_kernel(
    const float* __restrict__ x, const float* __restrict__ W_ih,
    const float* __restrict__ W_hh, const float* __restrict__ Wm,
    const float* __restrict__ Wv, const float* __restrict__ Wd1,
    const float* __restrict__ Wd2, char* __restrict__ ws) {
  long long i = (long long)blockIdx.x * 256 + threadIdx.x;
  if (i < 16777216LL) {  // x -> xbf  [B][T][DIN]
    ((__hip_bfloat16*)(ws + XBF_OFF))[i] = __float2bfloat16(x[i]);
    return;
  }
  i -= 16777216LL;
  if (i < 4718592LL) {  // Wg[4096][1152] = [W_ih | W_hh]
    int j = (int)(i / KG), k = (int)(i % KG);
    float v = (k < Sdim) ? W_ih[j * Sdim + k] : W_hh[(long long)j * Hdim + (k - Sdim)];
    ((__hip_bfloat16*)(ws + WG_OFF))[i] = __float2bfloat16(v);
    return;
  }
  i -= 4718592LL;
  if (i < 393216LL) {  // Wmv[256][1536] = [Wm ; Wv]
    int r = (int)(i / KP), k = (int)(i % KP);
    float v = (r < Sdim) ? Wm[r * KP + k] : Wv[(r - Sdim) * KP + k];
    ((__hip_bfloat16*)(ws + WMV_OFF))[i] = __float2bfloat16(v);
    return;
  }
  i -= 393216LL;
  if (i < 131072LL) { ((__hip_bfloat16*)(ws + WD1_OFF))[i] = __float2bfloat16(Wd1[i]); return; }
  i -= 131072LL;
  if (i < 524288LL) { ((__hip_bfloat16*)(ws + WD2_OFF))[i] = __float2bfloat16(Wd2[i]); return; }
  i -= 524288LL;
  if (i < 147456LL) { ((__hip_bfloat16*)(ws + AB_OFF))[i] = __float2bfloat16(0.0f); return; }  // [z0|h0]=0
  i -= 147456LL;
  if (i == 0) { *((float*)(ws + KL_OFF)) = 0.0f; return; }
  if (i == 1) { *((unsigned*)(ws + BAR_OFF)) = 0u; return; }        // barrier count
  if (i == 2) { *((unsigned*)(ws + BAR_OFF + 128)) = 0u; return; }  // barrier gen
}

// ---------------- device-scope generation barrier (all NBLK blocks resident)
__device__ __forceinline__ void gbar(unsigned* cnt, unsigned* gen) {
  __syncthreads();
  if (threadIdx.x == 0) {
    __threadfence();  // release all prior global writes (agent scope)
    unsigned g = __hip_atomic_load(gen, __ATOMIC_ACQUIRE, __HIP_MEMORY_SCOPE_AGENT);
    unsigned old = __hip_atomic_fetch_add(cnt, 1u, __ATOMIC_ACQ_REL, __HIP_MEMORY_SCOPE_AGENT);
    if (old == NBLK - 1) {
      __hip_atomic_store(cnt, 0u, __ATOMIC_RELAXED, __HIP_MEMORY_SCOPE_AGENT);
      __hip_atomic_store(gen, g + 1u, __ATOMIC_RELEASE, __HIP_MEMORY_SCOPE_AGENT);
    } else {
      while (__hip_atomic_load(gen, __ATOMIC_ACQUIRE, __HIP_MEMORY_SCOPE_AGENT) == g) {
        __builtin_amdgcn_s_sleep(2);
      }
    }
    __threadfence();  // acquire: invalidate caches before reading others' writes
  }
  __syncthreads();
}

// ---------------- persistent scan: whole T=256 recurrence in ONE kernel.
// Blocks 0..127:  gates GEMM [128,1152]x[1152,32] + LSTM cell (c in registers)
// Blocks 128..191: heads GEMM 16x16 tile (mean+logvar), K split over 4 waves
__global__ __launch_bounds__(256) void scan_kernel(
    char* __restrict__ ws, const float* __restrict__ noise,
    const float* __restrict__ b_ih, const float* __restrict__ b_hh,
    const float* __restrict__ bm, const float* __restrict__ bv) {
  const __hip_bfloat16* WG = (const __hip_bfloat16*)(ws + WG_OFF);
  const __hip_bfloat16* WMV = (const __hip_bfloat16*)(ws + WMV_OFF);
  const __hip_bfloat16* xbf = (const __hip_bfloat16*)(ws + XBF_OFF);
  __hip_bfloat16* zall = (__hip_bfloat16*)(ws + ZALL_OFF);
  float* klacc = (float*)(ws + KL_OFF);
  unsigned* bcnt = (unsigned*)(ws + BAR_OFF);
  unsigned* bgen = (unsigned*)(ws + BAR_OFF + 128);

  __shared__ float smem[4 * 128 * 9];  // gates: gsm[4][128][9]; heads: red[4][2][256]

  const int tid = threadIdx.x;
  const int lane = tid & 63;
  const int w = tid >> 6;
  const int row16 = lane & 15;
  const int quad = lane >> 4;
  const bool is_gates = (blockIdx.x < 128);

  // ---- gates-role registers
  const __hip_bfloat16* gb_bp0;  // B ptrs (N-tile 0/1) for this lane
  const __hip_bfloat16* gb_bp1;
  float bi[4], bf4[4], bg4[4], bo[4];  // per-thread gate biases (4 hcols)
  float creg[4] = {0.f, 0.f, 0.f, 0.f};
  int ew_row = 0, ew_hc0 = 0, ew_gcol0 = 0;
  // ---- heads-role registers
  const __hip_bfloat16* hd_bpm;
  const __hip_bfloat16* hd_bpv;
  int hd_mb = 0, hd_sb = 0;

  if (is_gates) {
    int ngrp = blockIdx.x;  // 8 H-cols: ngrp*8 .. +8
    // n_local = g*8+hc in [0,32); tile0: n 0..15 (gates 0,1), tile1: 16..31 (gates 2,3)
    int n0 = row16, n1 = 16 + row16;
    int grow0 = (n0 >> 3) * Hdim + ngrp * 8 + (n0 & 7);
    int grow1 = (n1 >> 3) * Hdim + ngrp * 8 + (n1 & 7);
    gb_bp0 = WG + (size_t)grow0 * KG;
    gb_bp1 = WG + (size_t)grow1 * KG;
    // elementwise ownership: thread covers elems e = tid*4..+3 of 128x8 patch
    ew_row = tid >> 1;
    ew_hc0 = (tid & 1) * 4;
    ew_gcol0 = ngrp * 8 + ew_hc0;
    #pragma unroll
    for (int u = 0; u < 4; u++) {
      int gc = ew_gcol0 + u;
      bi[u] = b_ih[gc] + b_hh[gc];
      bf4[u] = b_ih[Hdim + gc] + b_hh[Hdim + gc];
      bg4[u] = b_ih[2 * Hdim + gc] + b_hh[2 * Hdim + gc];
      bo[u] = b_ih[3 * Hdim + gc] + b_hh[3 * Hdim + gc];
    }
  } else {
    int hb = blockIdx.x - 128;
    hd_mb = hb >> 3;
    hd_sb = hb & 7;
    int s = hd_sb * 16 + row16;
    hd_bpm = WMV + (size_t)s * KP;
    hd_bpv = WMV + (size_t)(128 + s) * KP;
  }

  for (int t = 0; t < Tdim; t++) {
    const int par = t & 1;
    const __hip_bfloat16* Ab = (const __hip_bfloat16*)(ws + AB_OFF + (unsigned long long)par * AB_SZ);
    __hip_bfloat16* AbW = (__hip_bfloat16*)(ws + AB_OFF + (unsigned long long)(par ^ 1) * AB_SZ);

    if (is_gates) {
      // wave w: rows w*32..+32 (2 M-tiles) x 32 N-cols (2 N-tiles)
      const __hip_bfloat16* ap0 = Ab + (size_t)(w * 32 + row16) * KG;
      const __hip_bfloat16* ap1 = Ab + (size_t)(w * 32 + 16 + row16) * KG;
      floatx4 acc00 = {0.f,0.f,0.f,0.f}, acc01 = {0.f,0.f,0.f,0.f};
      floatx4 acc10 = {0.f,0.f,0.f,0.f}, acc11 = {0.f,0.f,0.f,0.f};
      #pragma unroll 4
      for (int kt = 0; kt < KG / 32; kt++) {
        int k0 = kt * 32 + quad * 8;
        short8 a0 = *(const short8*)(ap0 + k0);
        short8 a1 = *(const short8*)(ap1 + k0);
        short8 b0 = *(const short8*)(gb_bp0 + k0);
        short8 b1 = *(const short8*)(gb_bp1 + k0);
        acc00 = MFMA(a0, b0, acc00);
        acc01 = MFMA(a0, b1, acc01);
        acc10 = MFMA(a1, b0, acc10);
        acc11 = MFMA(a1, b1, acc11);
      }
      // scatter to LDS gsm[g][row][hc] (row-stride 9 floats to dodge conflicts)
      {
        int g0 = row16 >> 3, hc0 = row16 & 7;         // from N-tile 0
        int g1 = 2 + (row16 >> 3), hc1 = row16 & 7;   // from N-tile 1
        #pragma unroll
        for (int r = 0; r < 4; r++) {
          int rowA = w * 32 + quad * 4 + r;
          int rowB = w * 32 + 16 + quad * 4 + r;
          smem[(g0 * 128 + rowA) * 9 + hc0] = acc00[r];
          smem[(g1 * 128 + rowA) * 9 + hc1] = acc01[r];
          smem[(g0 * 128 + rowB) * 9 + hc0] = acc10[r];
          smem[(g1 * 128 + rowB) * 9 + hc1] = acc11[r];
        }
      }
      __syncthreads();
      // LSTM cell: 4 elems/thread, c in registers, write h (bf16) to AbW
      #pragma unroll
      for (int u = 0; u < 4; u++) {
        int hc = ew_hc0 + u;
        float iv = smem[(0 * 128 + ew_row) * 9 + hc] + bi[u];
        float fv = smem[(1 * 128 + ew_row) * 9 + hc] + bf4[u];
        float gv = smem[(2 * 128 + ew_row) * 9 + hc] + bg4[u];
        float ov = smem[(3 * 128 + ew_row) * 9 + hc] + bo[u];
        float cn = sigf(fv) * creg[u] + sigf(iv) * tanhfast(gv);
        creg[u] = cn;
        float hn = sigf(ov) * tanhfast(cn);
        AbW[(size_t)ew_row * KG + Sdim + ew_gcol0 + u] = __float2bfloat16(hn);
      }
      __syncthreads();  // protect smem before next-step reuse timing (cheap)
    }

    gbar(bcnt, bgen);  // h(t+1) complete & visible

    if (!is_gates) {
      // wave w: K-chunk [w*384, +384), A = [x_t | h_new] rows hd_mb*16..+16
      const __hip_bfloat16* axp = xbf + ((size_t)(hd_mb * 16 + row16) * Tdim + t) * DIN;
      const __hip_bfloat16* ahp = AbW + (size_t)(hd_mb * 16 + row16) * KG + Sdim;
      floatx4 am = {0.f,0.f,0.f,0.f}, av = {0.f,0.f,0.f,0.f};
      int kbase = w * 384;
      #pragma unroll 4
      for (int kt = 0; kt < 12; kt++) {
        int k0 = kbase + kt * 32 + quad * 8;
        short8 a = (k0 < DIN) ? *(const short8*)(axp + k0)
                              : *(const short8*)(ahp + (k0 - DIN));
        short8 b0 = *(const short8*)(hd_bpm + k0);
        short8 b1 = *(const short8*)(hd_bpv + k0);
        am = MFMA(a, b0, am);
        av = MFMA(a, b1, av);
      }
      // cross-wave K reduction through LDS: red[w][j][lane*4+r]
      #pragma unroll
      for (int r = 0; r < 4; r++) {
        smem[(w * 2 + 0) * 256 + lane * 4 + r] = am[r];
        smem[(w * 2 + 1) * 256 + lane * 4 + r] = av[r];
      }
      __syncthreads();
      if (w == 0) {
        float kls = 0.0f;
        #pragma unroll
        for (int r = 0; r < 4; r++) {
          int idx = lane * 4 + r;
          float mean = smem[0 * 256 + idx] + smem[2 * 256 + idx] +
                       smem[4 * 256 + idx] + smem[6 * 256 + idx];
          float lv = smem[1 * 256 + idx] + smem[3 * 256 + idx] +
                     smem[5 * 256 + idx] + smem[7 * 256 + idx];
          int b = hd_mb * 16 + quad * 4 + r;
          int s = hd_sb * 16 + row16;
          mean += bm[s];
          lv += bv[s];
          float std = __expf(0.5f * lv);
          float nt = noise[((size_t)b * Tdim + t) * Sdim + s];
          float z = nt * std + mean;
          __hip_bfloat16 zb = __float2bfloat16(z);
          zall[((size_t)b * Tdim + t) * Sdim + s] = zb;
          AbW[(size_t)b * KG + s] = zb;
          kls += std * std + mean * mean - 0.5f * lv - 0.5f;  // log(std)=0.5*lv
        }
        #pragma unroll
        for (int off = 32; off > 0; off >>= 1) kls += __shfl_down(kls, off, 64);
        if (lane == 0) atomicAdd(klacc, kls);
      }
      __syncthreads();
    }

    gbar(bcnt, bgen);  // z(t+1) complete & visible
  }
}

// ---------------- decoder GEMM1: Hbuf = relu(zall[32768,128] @ Wd1^T + bd1) -> bf16
__global__ __launch_bounds__(256) void dec1_kernel(char* __restrict__ ws,
                                                   const float* __restrict__ bd1) {
  const __hip_bfloat16* zall = (const __hip_bfloat16*)(ws + ZALL_OFF);
  const __hip_bfloat16* Wd1b = (const __hip_bfloat16*)(ws + WD1_OFF);
  __hip_bfloat16* Hbuf = (__hip_bfloat16*)(ws + HB_OFF);
  int tid = threadIdx.x, lane = tid & 63, w = tid >> 6;
  int mb = blockIdx.x, nb = blockIdx.y;
  int row16 = lane & 15, quad = lane >> 4;
  int arow = mb * 64 + w * 16 + row16;
  const __hip_bfloat16* aptr = zall + (size_t)arow * Sdim;
  floatx4 acc[4] = {{0.f,0.f,0.f,0.f},{0.f,0.f,0.f,0.f},{0.f,0.f,0.f,0.f},{0.f,0.f,0.f,0.f}};
  #pragma unroll
  for (int kt = 0; kt < Sdim / 32; kt++) {
    int k0 = kt * 32 + quad * 8;
    short8 a = *(const short8*)(aptr + k0);
    #pragma unroll
    for (int j = 0; j < 4; j++) {
      const __hip_bfloat16* bp = Wd1b + (size_t)(nb * 64 + j * 16 + row16) * Sdim;
      acc[j] = MFMA(a, *(const short8*)(bp + k0), acc[j]);
    }
  }
  #pragma unroll
  for (int j = 0; j < 4; j++) {
    int n = nb * 64 + j * 16 + row16;
    float bias = bd1[n];
    #pragma unroll
    for (int r = 0; r < 4; r++) {
      int rr = mb * 64 + w * 16 + quad * 4 + r;
      float v = fmaxf(acc[j][r] + bias, 0.0f);
      Hbuf[(size_t)rr * DHdim + n] = __float2bfloat16(v);
    }
  }
}

// ---------------- decoder GEMM2: out = Hbuf[32768,1024] @ Wd2^T + bd2 -> f32
__global__ __launch_bounds__(256) void dec2_kernel(char* __restrict__ ws,
                                                   const float* __restrict__ bd2,
                                                   float* __restrict__ out) {
  const __hip_bfloat16* Hbuf = (const __hip_bfloat16*)(ws + HB_OFF);
  const __hip_bfloat16* Wd2b = (const __hip_bfloat16*)(ws + WD2_OFF);
  int tid = threadIdx.x, lane = tid & 63, w = tid >> 6;
  int mb = blockIdx.x, nb = blockIdx.y;
  int row16 = lane & 15, quad = lane >> 4;
  int arow = mb * 64 + w * 16 + row16;
  const __hip_bfloat16* aptr = Hbuf + (size_t)arow * DHdim;
  const __hip_bfloat16* bp[4];
  #pragma unroll
  for (int j = 0; j < 4; j++) bp[j] = Wd2b + (size_t)(nb * 64 + j * 16 + row16) * DHdim;
  floatx4 acc[4] = {{0.f,0.f,0.f,0.f},{0.f,0.f,0.f,0.f},{0.f,0.f,0.f,0.f},{0.f,0.f,0.f,0.f}};
  for (int kt = 0; kt < DHdim / 32; kt++) {
    int k0 = kt * 32 + quad * 8;
    short8 a = *(const short8*)(aptr + k0);
    #pragma unroll
    for (int j = 0; j < 4; j++)
      acc[j] = MFMA(a, *(const short8*)(bp[j] + k0), acc[j]);
  }
  #pragma unroll
  for (int j = 0; j < 4; j++) {
    int n = nb * 64 + j * 16 + row16;
    float bias = bd2[n];
    #pragma unroll
    for (int r = 0; r < 4; r++) {
      int rr = mb * 64 + w * 16 + quad * 4 + r;
      out[(size_t)rr * DIN + n] = acc[j][r] + bias;
    }
  }
}

__global__ void kl_write_kernel(const char* __restrict__ ws, float* __restrict__ out) {
  if (threadIdx.x == 0 && blockIdx.x == 0)
    out[16777216] = *(const float*)(ws + KL_OFF);
}

extern "C" void kernel_launch(void* const* d_in, const int* in_sizes, int n_in,
                              void* d_out, int out_size, void* d_ws, size_t ws_size,
                              hipStream_t stream) {
  const float* x = (const float*)d_in[0];
  const float* noise = (const float*)d_in[1];
  const float* W_ih = (const float*)d_in[2];
  const float* W_hh = (const float*)d_in[3];
  const float* b_ih = (const float*)d_in[4];
  const float* b_hh = (const float*)d_in[5];
  const float* Wm = (const float*)d_in[6];
  const float* bm = (const float*)d_in[7];
  const float* Wv = (const float*)d_in[8];
  const float* bv = (const float*)d_in[9];
  const float* Wd1 = (const float*)d_in[10];
  const float* bd1 = (const float*)d_in[11];
  const float* Wd2 = (const float*)d_in[12];
  const float* bd2 = (const float*)d_in[13];
  char* ws = (char*)d_ws;
  float* out = (float*)d_out;

  long long total_prep = 22691843LL;
  int pblocks = (int)((total_prep + 255) / 256);
  prep_kernel<<<pblocks, 256, 0, stream>>>(x, W_ih, W_hh, Wm, Wv, Wd1, Wd2, ws);
  scan_kernel<<<NBLK, 256, 0, stream>>>(ws, noise, b_ih, b_hh, bm, bv);
  dec1_kernel<<<dim3(512, 16), 256, 0, stream>>>(ws, bd1);
  dec2_kernel<<<dim3(512, 8), 256, 0, stream>>>(ws, bd2, out);
  kl_write_kernel<<<1, 64, 0, stream>>>(ws, out);
}

// Round 3
// 10023.980 us; speedup vs baseline: 2.2335x; 2.2335x over previous
//
#include <hip/hip_runtime.h>
#include <hip/hip_bf16.h>

#define Bdim 128
#define Tdim 256
#define DIN 512
#define Hdim 1024
#define Sdim 128
#define DHdim 1024
#define KG 1152   // S + H (gates GEMM K)
#define KP 1536   // DIN + H (heads GEMM K)
#define NBLK 192  // persistent: 128 gates blocks + 64 heads blocks

using short8  = __attribute__((ext_vector_type(8))) short;   // 8 bf16 (4 VGPRs)
using floatx4 = __attribute__((ext_vector_type(4))) float;   // MFMA accum

#define MFMA(a, b, c) __builtin_amdgcn_mfma_f32_16x16x32_bf16((a), (b), (c), 0, 0, 0)

// ---- workspace layout (bytes). Scan-phase staging (xbf/Wg/Wmv) unions with
// Hbuf (decoder intermediate), which is written only after the scan finishes.
#define XBF_OFF   0ull            // 128*256*512 bf16 = 33,554,432
#define WG_OFF    33554432ull     // 4096*1152 bf16 = 9,437,184
#define WMV_OFF   42991616ull     // 256*1536 bf16 = 786,432
#define HB_OFF    0ull            // 32768*1024 bf16 = 67,108,864 (unions scan staging)
#define WD1_OFF   67108864ull     // 1024*128 bf16 = 262,144
#define WD2_OFF   67371008ull     // 512*1024 bf16 = 1,048,576
#define AB_OFF    68419584ull     // 2 x 128*1152 bf16 (ping-pong [z|h]) = 589,824
#define AB_SZ     294912ull
#define ZALL_OFF  69009408ull     // 32768*128 bf16 = 8,388,608
#define KL_OFF    77398016ull     // 1 f32
#define BAR_OFF   77398144ull     // cnt0 @+0, cnt1 @+128, gen @+256

__device__ __forceinline__ float sigf(float v) { return 1.0f / (1.0f + __expf(-v)); }
__device__ __forceinline__ float tanhfast(float v) { return 1.0f - 2.0f / (__expf(2.0f * v) + 1.0f); }

// memory-side (cross-XCD coherent) accesses — no cache maintenance needed
__device__ __forceinline__ short8 aload16(const __hip_bfloat16* p) {
  union { unsigned long long u[2]; short8 s; } r;
  unsigned long long* q = (unsigned long long*)p;
  r.u[0] = __hip_atomic_load(q,     __ATOMIC_RELAXED, __HIP_MEMORY_SCOPE_AGENT);
  r.u[1] = __hip_atomic_load(q + 1, __ATOMIC_RELAXED, __HIP_MEMORY_SCOPE_AGENT);
  return r.s;
}
__device__ __forceinline__ void astore8(__hip_bfloat16* p, unsigned long long v) {
  __hip_atomic_store((unsigned long long*)p, v, __ATOMIC_RELAXED, __HIP_MEMORY_SCOPE_AGENT);
}
__device__ __forceinline__ void astore4(__hip_bfloat16* p, unsigned v) {
  __hip_atomic_store((unsigned*)p, v, __ATOMIC_RELAXED, __HIP_MEMORY_SCOPE_AGENT);
}

// ---------------- prep: fp32->bf16 conversions, weight packing, state zeroing
__global__ __launch_bounds__(256) void prep_kernel(
    const float* __restrict__ x, const float* __restrict__ W_ih,
    const float* __restrict__ W_hh, const float* __restrict__ Wm,
    const float* __restrict__ Wv, const float* __restrict__ Wd1,
    const float* __restrict__ Wd2, char* __restrict__ ws) {
  long long i = (long long)blockIdx.x * 256 + threadIdx.x;
  if (i < 16777216LL) {  // x -> xbf  [B][T][DIN]
    ((__hip_bfloat16*)(ws + XBF_OFF))[i] = __float2bfloat16(x[i]);
    return;
  }
  i -= 16777216LL;
  if (i < 4718592LL) {  // Wg[4096][1152] = [W_ih | W_hh]
    int j = (int)(i / KG), k = (int)(i % KG);
    float v = (k < Sdim) ? W_ih[j * Sdim + k] : W_hh[(long long)j * Hdim + (k - Sdim)];
    ((__hip_bfloat16*)(ws + WG_OFF))[i] = __float2bfloat16(v);
    return;
  }
  i -= 4718592LL;
  if (i < 393216LL) {  // Wmv[256][1536] = [Wm ; Wv]
    int r = (int)(i / KP), k = (int)(i % KP);
    float v = (r < Sdim) ? Wm[r * KP + k] : Wv[(r - Sdim) * KP + k];
    ((__hip_bfloat16*)(ws + WMV_OFF))[i] = __float2bfloat16(v);
    return;
  }
  i -= 393216LL;
  if (i < 131072LL) { ((__hip_bfloat16*)(ws + WD1_OFF))[i] = __float2bfloat16(Wd1[i]); return; }
  i -= 131072LL;
  if (i < 524288LL) { ((__hip_bfloat16*)(ws + WD2_OFF))[i] = __float2bfloat16(Wd2[i]); return; }
  i -= 524288LL;
  if (i < 147456LL) { ((__hip_bfloat16*)(ws + AB_OFF))[i] = __float2bfloat16(0.0f); return; }  // [z0|h0]=0
  i -= 147456LL;
  if (i == 0) { *((float*)(ws + KL_OFF)) = 0.0f; return; }
  if (i == 1) { *((unsigned*)(ws + BAR_OFF)) = 0u; return; }
  if (i == 2) { *((unsigned*)(ws + BAR_OFF + 128)) = 0u; return; }
  if (i == 3) { *((unsigned*)(ws + BAR_OFF + 256)) = 0u; return; }
}

// ---------------- fence-free device barrier: relaxed atomics only.
// Two phase-indexed counters avoid reset races; s_waitcnt orders reset<flip.
// Data coherence is carried by the memory-side atomics, not by this barrier.
__device__ __forceinline__ void gbar(char* ws, unsigned phase) {
  __syncthreads();  // drains each wave's vmem (incl. atomic stores) before s_barrier
  if (threadIdx.x == 0) {
    unsigned* cnt = (unsigned*)(ws + BAR_OFF + (unsigned long long)(phase & 1u) * 128u);
    unsigned* gen = (unsigned*)(ws + BAR_OFF + 256u);
    unsigned g = __hip_atomic_load(gen, __ATOMIC_RELAXED, __HIP_MEMORY_SCOPE_AGENT);
    unsigned old = __hip_atomic_fetch_add(cnt, 1u, __ATOMIC_RELAXED, __HIP_MEMORY_SCOPE_AGENT);
    if (old == NBLK - 1u) {
      __hip_atomic_store(cnt, 0u, __ATOMIC_RELAXED, __HIP_MEMORY_SCOPE_AGENT);
      __builtin_amdgcn_s_waitcnt(0);  // reset acked before flip
      __hip_atomic_store(gen, g + 1u, __ATOMIC_RELAXED, __HIP_MEMORY_SCOPE_AGENT);
    } else {
      while (__hip_atomic_load(gen, __ATOMIC_RELAXED, __HIP_MEMORY_SCOPE_AGENT) == g)
        __builtin_amdgcn_s_sleep(1);
    }
  }
  __syncthreads();
}

// ---------------- persistent scan: whole T=256 recurrence in ONE kernel.
// Blocks 0..127 (mhalf = bid>>6, ngrp = bid&63): gates GEMM M=64 rows x N=64
//   (4 gate-tiles x 16 H-cols) + LSTM cell; c in registers; bias in acc-init.
// Blocks 128..191: heads 16x16 tile (mean+logvar), K=1536 split over 4 waves.
__global__ __launch_bounds__(256) void scan_kernel(
    char* __restrict__ ws, const float* __restrict__ noise,
    const float* __restrict__ b_ih, const float* __restrict__ b_hh,
    const float* __restrict__ bm, const float* __restrict__ bv) {
  const __hip_bfloat16* WG = (const __hip_bfloat16*)(ws + WG_OFF);
  const __hip_bfloat16* WMV = (const __hip_bfloat16*)(ws + WMV_OFF);
  const __hip_bfloat16* xbf = (const __hip_bfloat16*)(ws + XBF_OFF);
  __hip_bfloat16* zall = (__hip_bfloat16*)(ws + ZALL_OFF);
  float* klacc = (float*)(ws + KL_OFF);

  __shared__ float smem[4 * 64 * 17];  // gates gsm[4][64][17]; heads red[8][256]

  const int tid = threadIdx.x;
  const int lane = tid & 63;
  const int w = tid >> 6;
  const int row16 = lane & 15;
  const int quad = lane >> 4;
  const bool is_gates = (blockIdx.x < 128);

  // ---- gates-role setup
  const __hip_bfloat16* gb_bp[4];
  float biasv[4];
  int mhalf = 0, ngrp = 0, ew_lrow = 0, ew_hcb = 0;
  float creg[4] = {0.f, 0.f, 0.f, 0.f};
  // ---- heads-role setup
  const __hip_bfloat16* hd_bpm = nullptr;
  const __hip_bfloat16* hd_bpv = nullptr;
  int hd_mb = 0, hd_sb = 0;
  float hbm = 0.f, hbv = 0.f;

  if (is_gates) {
    mhalf = blockIdx.x >> 6;
    ngrp = blockIdx.x & 63;
    #pragma unroll
    for (int j = 0; j < 4; j++) {
      int idx = j * Hdim + ngrp * 16 + row16;  // gate j, hcol = ngrp*16+row16
      gb_bp[j] = WG + (size_t)idx * KG;
      biasv[j] = b_ih[idx] + b_hh[idx];
    }
    ew_lrow = tid >> 2;          // local row 0..63
    ew_hcb = (tid & 3) * 4;      // 4 consecutive hcols -> one 8B store
  } else {
    int hb = blockIdx.x - 128;
    hd_mb = hb >> 3;
    hd_sb = hb & 7;
    int s = hd_sb * 16 + row16;
    hd_bpm = WMV + (size_t)s * KP;
    hd_bpv = WMV + (size_t)(128 + s) * KP;
    hbm = bm[s];
    hbv = bv[s];
  }

  unsigned ph = 0;
  for (int t = 0; t < Tdim; t++) {
    const int par = t & 1;
    const __hip_bfloat16* Ab = (const __hip_bfloat16*)(ws + AB_OFF + (unsigned long long)par * AB_SZ);
    __hip_bfloat16* AbW = (__hip_bfloat16*)(ws + AB_OFF + (unsigned long long)(par ^ 1) * AB_SZ);

    if (is_gates) {
      // wave w: rows mhalf*64 + w*16 .. +16 ; N = 4 gate-tiles of 16
      const __hip_bfloat16* aptr = Ab + (size_t)(mhalf * 64 + w * 16 + row16) * KG;
      floatx4 acc[4];
      #pragma unroll
      for (int j = 0; j < 4; j++)
        acc[j] = (floatx4){biasv[j], biasv[j], biasv[j], biasv[j]};
      #pragma unroll 4
      for (int kt = 0; kt < KG / 32; kt++) {
        int k0 = kt * 32 + quad * 8;
        short8 a = aload16(aptr + k0);   // shared A: memory-side load
        #pragma unroll
        for (int j = 0; j < 4; j++)
          acc[j] = MFMA(a, *(const short8*)(gb_bp[j] + k0), acc[j]);
      }
      // scatter to gsm[j][lrow][hc] (stride 17 floats)
      #pragma unroll
      for (int j = 0; j < 4; j++) {
        #pragma unroll
        for (int r = 0; r < 4; r++) {
          int lr = w * 16 + quad * 4 + r;
          smem[(j * 64 + lr) * 17 + row16] = acc[j][r];
        }
      }
      __syncthreads();
      // LSTM cell: 4 consecutive hcols/thread, c in regs, one 8B atomic h-store
      {
        int grow = mhalf * 64 + ew_lrow;
        union { unsigned long long u; unsigned short s[4]; } hp;
        #pragma unroll
        for (int u = 0; u < 4; u++) {
          int hc = ew_hcb + u;
          float iv = smem[(0 * 64 + ew_lrow) * 17 + hc];
          float fv = smem[(1 * 64 + ew_lrow) * 17 + hc];
          float gv = smem[(2 * 64 + ew_lrow) * 17 + hc];
          float ov = smem[(3 * 64 + ew_lrow) * 17 + hc];
          float cn = sigf(fv) * creg[u] + sigf(iv) * tanhfast(gv);
          creg[u] = cn;
          float hn = sigf(ov) * tanhfast(cn);
          __hip_bfloat16 hb = __float2bfloat16(hn);
          hp.s[u] = reinterpret_cast<unsigned short&>(hb);
        }
        astore8(AbW + (size_t)grow * KG + Sdim + ngrp * 16 + ew_hcb, hp.u);
      }
    }

    gbar(ws, ph++);  // h(t+1) at coherence point

    if (!is_gates) {
      // wave w: K-chunk [w*384, +384); A = [x_t (cached) | h_new (atomic)]
      const __hip_bfloat16* axp = xbf + ((size_t)(hd_mb * 16 + row16) * Tdim + t) * DIN;
      const __hip_bfloat16* ahp = AbW + (size_t)(hd_mb * 16 + row16) * KG + Sdim;
      floatx4 am, av;
      if (w == 0) { am = (floatx4){hbm, hbm, hbm, hbm}; av = (floatx4){hbv, hbv, hbv, hbv}; }
      else        { am = (floatx4){0.f, 0.f, 0.f, 0.f}; av = (floatx4){0.f, 0.f, 0.f, 0.f}; }
      int kbase = w * 384;
      #pragma unroll 4
      for (int kt = 0; kt < 12; kt++) {
        int k0 = kbase + kt * 32 + quad * 8;
        short8 a = (k0 < DIN) ? *(const short8*)(axp + k0)
                              : aload16(ahp + (k0 - DIN));
        am = MFMA(a, *(const short8*)(hd_bpm + k0), am);
        av = MFMA(a, *(const short8*)(hd_bpv + k0), av);
      }
      #pragma unroll
      for (int r = 0; r < 4; r++) {
        smem[(w * 2 + 0) * 256 + lane * 4 + r] = am[r];
        smem[(w * 2 + 1) * 256 + lane * 4 + r] = av[r];
      }
      __syncthreads();
      if (w == 0) {
        float kls = 0.0f;
        #pragma unroll
        for (int r = 0; r < 4; r++) {
          int idx = lane * 4 + r;
          float mean = smem[0 * 256 + idx] + smem[2 * 256 + idx] +
                       smem[4 * 256 + idx] + smem[6 * 256 + idx];
          float lv = smem[1 * 256 + idx] + smem[3 * 256 + idx] +
                     smem[5 * 256 + idx] + smem[7 * 256 + idx];
          int b = hd_mb * 16 + quad * 4 + r;
          int s = hd_sb * 16 + row16;
          float std = __expf(0.5f * lv);
          float nt = noise[((size_t)b * Tdim + t) * Sdim + s];
          float z = nt * std + mean;
          __hip_bfloat16 zb = __float2bfloat16(z);
          zall[((size_t)b * Tdim + t) * Sdim + s] = zb;  // scan-private: normal store
          // pack (s even, s+1) into one 4B memory-side store via lane pairing
          float zo = __shfl_xor(z, 1, 64);
          if ((row16 & 1) == 0) {
            __hip_bfloat16 zb2 = __float2bfloat16(zo);
            unsigned lo = reinterpret_cast<unsigned short&>(zb);
            unsigned hi = reinterpret_cast<unsigned short&>(zb2);
            astore4(AbW + (size_t)b * KG + s, lo | (hi << 16));
          }
          kls += std * std + mean * mean - 0.5f * lv - 0.5f;  // log(std)=0.5*lv
        }
        #pragma unroll
        for (int off = 32; off > 0; off >>= 1) kls += __shfl_down(kls, off, 64);
        if (lane == 0) atomicAdd(klacc, kls);
      }
    }

    gbar(ws, ph++);  // z(t+1) at coherence point
  }
}

// ---------------- decoder GEMM1: Hbuf = relu(zall[32768,128] @ Wd1^T + bd1) -> bf16
__global__ __launch_bounds__(256) void dec1_kernel(char* __restrict__ ws,
                                                   const float* __restrict__ bd1) {
  const __hip_bfloat16* zall = (const __hip_bfloat16*)(ws + ZALL_OFF);
  const __hip_bfloat16* Wd1b = (const __hip_bfloat16*)(ws + WD1_OFF);
  __hip_bfloat16* Hbuf = (__hip_bfloat16*)(ws + HB_OFF);
  int tid = threadIdx.x, lane = tid & 63, w = tid >> 6;
  int mb = blockIdx.x, nb = blockIdx.y;
  int row16 = lane & 15, quad = lane >> 4;
  int arow = mb * 64 + w * 16 + row16;
  const __hip_bfloat16* aptr = zall + (size_t)arow * Sdim;
  floatx4 acc[4] = {{0.f,0.f,0.f,0.f},{0.f,0.f,0.f,0.f},{0.f,0.f,0.f,0.f},{0.f,0.f,0.f,0.f}};
  #pragma unroll
  for (int kt = 0; kt < Sdim / 32; kt++) {
    int k0 = kt * 32 + quad * 8;
    short8 a = *(const short8*)(aptr + k0);
    #pragma unroll
    for (int j = 0; j < 4; j++) {
      const __hip_bfloat16* bp = Wd1b + (size_t)(nb * 64 + j * 16 + row16) * Sdim;
      acc[j] = MFMA(a, *(const short8*)(bp + k0), acc[j]);
    }
  }
  #pragma unroll
  for (int j = 0; j < 4; j++) {
    int n = nb * 64 + j * 16 + row16;
    float bias = bd1[n];
    #pragma unroll
    for (int r = 0; r < 4; r++) {
      int rr = mb * 64 + w * 16 + quad * 4 + r;
      float v = fmaxf(acc[j][r] + bias, 0.0f);
      Hbuf[(size_t)rr * DHdim + n] = __float2bfloat16(v);
    }
  }
}

// ---------------- decoder GEMM2: out = Hbuf[32768,1024] @ Wd2^T + bd2 -> f32
__global__ __launch_bounds__(256) void dec2_kernel(char* __restrict__ ws,
                                                   const float* __restrict__ bd2,
                                                   float* __restrict__ out) {
  const __hip_bfloat16* Hbuf = (const __hip_bfloat16*)(ws + HB_OFF);
  const __hip_bfloat16* Wd2b = (const __hip_bfloat16*)(ws + WD2_OFF);
  int tid = threadIdx.x, lane = tid & 63, w = tid >> 6;
  int mb = blockIdx.x, nb = blockIdx.y;
  int row16 = lane & 15, quad = lane >> 4;
  int arow = mb * 64 + w * 16 + row16;
  const __hip_bfloat16* aptr = Hbuf + (size_t)arow * DHdim;
  const __hip_bfloat16* bp[4];
  #pragma unroll
  for (int j = 0; j < 4; j++) bp[j] = Wd2b + (size_t)(nb * 64 + j * 16 + row16) * DHdim;
  floatx4 acc[4] = {{0.f,0.f,0.f,0.f},{0.f,0.f,0.f,0.f},{0.f,0.f,0.f,0.f},{0.f,0.f,0.f,0.f}};
  for (int kt = 0; kt < DHdim / 32; kt++) {
    int k0 = kt * 32 + quad * 8;
    short8 a = *(const short8*)(aptr + k0);
    #pragma unroll
    for (int j = 0; j < 4; j++)
      acc[j] = MFMA(a, *(const short8*)(bp[j] + k0), acc[j]);
  }
  #pragma unroll
  for (int j = 0; j < 4; j++) {
    int n = nb * 64 + j * 16 + row16;
    float bias = bd2[n];
    #pragma unroll
    for (int r = 0; r < 4; r++) {
      int rr = mb * 64 + w * 16 + quad * 4 + r;
      out[(size_t)rr * DIN + n] = acc[j][r] + bias;
    }
  }
}

__global__ void kl_write_kernel(const char* __restrict__ ws, float* __restrict__ out) {
  if (threadIdx.x == 0 && blockIdx.x == 0)
    out[16777216] = *(const float*)(ws + KL_OFF);
}

extern "C" void kernel_launch(void* const* d_in, const int* in_sizes, int n_in,
                              void* d_out, int out_size, void* d_ws, size_t ws_size,
                              hipStream_t stream) {
  const float* x = (const float*)d_in[0];
  const float* noise = (const float*)d_in[1];
  const float* W_ih = (const float*)d_in[2];
  const float* W_hh = (const float*)d_in[3];
  const float* b_ih = (const float*)d_in[4];
  const float* b_hh = (const float*)d_in[5];
  const float* Wm = (const float*)d_in[6];
  const float* bm = (const float*)d_in[7];
  const float* Wv = (const float*)d_in[8];
  const float* bv = (const float*)d_in[9];
  const float* Wd1 = (const float*)d_in[10];
  const float* bd1 = (const float*)d_in[11];
  const float* Wd2 = (const float*)d_in[12];
  const float* bd2 = (const float*)d_in[13];
  char* ws = (char*)d_ws;
  float* out = (float*)d_out;

  long long total_prep = 22691844LL;
  int pblocks = (int)((total_prep + 255) / 256);
  prep_kernel<<<pblocks, 256, 0, stream>>>(x, W_ih, W_hh, Wm, Wv, Wd1, Wd2, ws);
  scan_kernel<<<NBLK, 256, 0, stream>>>(ws, noise, b_ih, b_hh, bm, bv);
  dec1_kernel<<<dim3(512, 16), 256, 0, stream>>>(ws, bd1);
  dec2_kernel<<<dim3(512, 8), 256, 0, stream>>>(ws, bd2, out);
  kl_write_kernel<<<1, 64, 0, stream>>>(ws, out);
}

// Round 4
// 7587.167 us; speedup vs baseline: 2.9508x; 1.3212x over previous
//
#include <hip/hip_runtime.h>
#include <hip/hip_bf16.h>

#define Bdim 128
#define Tdim 256
#define DIN 512
#define Hdim 1024
#define Sdim 128
#define DHdim 1024
#define KG 1152   // S + H (gates GEMM K)
#define KP 1536   // DIN + H (heads GEMM K)
#define NBLK 192  // persistent: 128 gates blocks + 64 heads blocks

using short8  = __attribute__((ext_vector_type(8))) short;   // 8 bf16 (4 VGPRs)
using floatx4 = __attribute__((ext_vector_type(4))) float;   // MFMA accum

#define MFMA(a, b, c) __builtin_amdgcn_mfma_f32_16x16x32_bf16((a), (b), (c), 0, 0, 0)

// ---- workspace layout (bytes). Scan-phase staging (xbf/Wg/Wmv) unions with
// Hbuf (decoder intermediate), which is written only after the scan finishes.
#define XBF_OFF   0ull            // 128*256*512 bf16 = 33,554,432
#define WG_OFF    33554432ull     // 4096*1152 bf16 = 9,437,184
#define WMV_OFF   42991616ull     // 256*1536 bf16 = 786,432
#define HB_OFF    0ull            // 32768*1024 bf16 = 67,108,864 (unions scan staging)
#define WD1_OFF   67108864ull     // 1024*128 bf16 = 262,144
#define WD2_OFF   67371008ull     // 512*1024 bf16 = 1,048,576
#define AB_OFF    68419584ull     // 2 x 128*1152 bf16 (ping-pong [z|h]) = 589,824
#define AB_SZ     294912ull
#define ZALL_OFF  69009408ull     // 32768*128 bf16 = 8,388,608
#define KL_OFF    77398016ull     // 1 f32
#define FLG_OFF   77398144ull     // 192 x u32 monotonic per-producer seqno flags

__device__ __forceinline__ float sigf(float v) { return 1.0f / (1.0f + __expf(-v)); }
__device__ __forceinline__ float tanhfast(float v) { return 1.0f - 2.0f / (__expf(2.0f * v) + 1.0f); }

// memory-side (cross-XCD coherent) accesses — no cache maintenance needed
__device__ __forceinline__ short8 aload16(const __hip_bfloat16* p) {
  union { unsigned long long u[2]; short8 s; } r;
  unsigned long long* q = (unsigned long long*)p;
  r.u[0] = __hip_atomic_load(q,     __ATOMIC_RELAXED, __HIP_MEMORY_SCOPE_AGENT);
  r.u[1] = __hip_atomic_load(q + 1, __ATOMIC_RELAXED, __HIP_MEMORY_SCOPE_AGENT);
  return r.s;
}
__device__ __forceinline__ void astore4(__hip_bfloat16* p, unsigned v) {
  __hip_atomic_store((unsigned*)(void*)p, v, __ATOMIC_RELAXED, __HIP_MEMORY_SCOPE_AGENT);
}

// lane-parallel flag wait: lane polls flags[base + (lane & mask)] until ALL >= target.
// One coalesced 4B load per round + 64-lane ballot; flags are monotonic (no resets).
__device__ __forceinline__ void waitflags(unsigned* flags, int base, int mask,
                                          unsigned target, int lane) {
  unsigned* p = flags + base + (lane & mask);
  while (!__all((int)(__hip_atomic_load(p, __ATOMIC_RELAXED, __HIP_MEMORY_SCOPE_AGENT) >= target))) {
    __builtin_amdgcn_s_sleep(1);
  }
}

// ---------------- prep: fp32->bf16 conversions, weight packing, state zeroing
__global__ __launch_bounds__(256) void prep_kernel(
    const float* __restrict__ x, const float* __restrict__ W_ih,
    const float* __restrict__ W_hh, const float* __restrict__ Wm,
    const float* __restrict__ Wv, const float* __restrict__ Wd1,
    const float* __restrict__ Wd2, char* __restrict__ ws) {
  long long i = (long long)blockIdx.x * 256 + threadIdx.x;
  if (i < 16777216LL) {  // x -> xbf  [B][T][DIN]
    ((__hip_bfloat16*)(ws + XBF_OFF))[i] = __float2bfloat16(x[i]);
    return;
  }
  i -= 16777216LL;
  if (i < 4718592LL) {  // Wg[4096][1152] = [W_ih | W_hh]
    int j = (int)(i / KG), k = (int)(i % KG);
    float v = (k < Sdim) ? W_ih[j * Sdim + k] : W_hh[(long long)j * Hdim + (k - Sdim)];
    ((__hip_bfloat16*)(ws + WG_OFF))[i] = __float2bfloat16(v);
    return;
  }
  i -= 4718592LL;
  if (i < 393216LL) {  // Wmv[256][1536] = [Wm ; Wv]
    int r = (int)(i / KP), k = (int)(i % KP);
    float v = (r < Sdim) ? Wm[r * KP + k] : Wv[(r - Sdim) * KP + k];
    ((__hip_bfloat16*)(ws + WMV_OFF))[i] = __float2bfloat16(v);
    return;
  }
  i -= 393216LL;
  if (i < 131072LL) { ((__hip_bfloat16*)(ws + WD1_OFF))[i] = __float2bfloat16(Wd1[i]); return; }
  i -= 131072LL;
  if (i < 524288LL) { ((__hip_bfloat16*)(ws + WD2_OFF))[i] = __float2bfloat16(Wd2[i]); return; }
  i -= 524288LL;
  if (i < 147456LL) { ((__hip_bfloat16*)(ws + AB_OFF))[i] = __float2bfloat16(0.0f); return; }  // [z0|h0]=0
  i -= 147456LL;
  if (i == 0) { *((float*)(ws + KL_OFF)) = 0.0f; return; }
  i -= 1;
  if (i < 192LL) { ((unsigned*)(ws + FLG_OFF))[i] = 0u; return; }
}

// ---------------- persistent scan: whole T=256 recurrence in ONE kernel.
// No device-wide barrier: per-producer monotonic seqno flags.
//   gates block b<128 (mhalf=b>>6, ngrp=b&63): M=64 rows x N=64 (4 gate-tiles of
//   16 hcols, same hcol set -> LSTM is lane-local, no LDS); c in registers.
//   heads block 128+hb (mb=hb>>3, sb=hb&7): 16x16 tile (mean+logvar), K over 4 waves.
__global__ __launch_bounds__(256, 1) void scan_kernel(
    char* __restrict__ ws, const float* __restrict__ noise,
    const float* __restrict__ b_ih, const float* __restrict__ b_hh,
    const float* __restrict__ bm, const float* __restrict__ bv) {
  const __hip_bfloat16* WG = (const __hip_bfloat16*)(ws + WG_OFF);
  const __hip_bfloat16* WMV = (const __hip_bfloat16*)(ws + WMV_OFF);
  const __hip_bfloat16* xbf = (const __hip_bfloat16*)(ws + XBF_OFF);
  __hip_bfloat16* zall = (__hip_bfloat16*)(ws + ZALL_OFF);
  float* klacc = (float*)(ws + KL_OFF);
  unsigned* flags = (unsigned*)(ws + FLG_OFF);

  __shared__ float smem[8 * 256];  // heads cross-wave reduction only

  const int tid = threadIdx.x;
  const int lane = tid & 63;
  const int w = tid >> 6;
  const int row16 = lane & 15;
  const int quad = lane >> 4;
  const bool is_gates = (blockIdx.x < 128);

  // ---- gates-role setup
  const __hip_bfloat16* gb_bp[4];
  float biasv[4];
  int mhalf = 0, ngrp = 0;
  float creg[4] = {0.f, 0.f, 0.f, 0.f};
  // ---- heads-role setup
  const __hip_bfloat16* hd_bpm = nullptr;
  const __hip_bfloat16* hd_bpv = nullptr;
  int hd_mb = 0, hd_sb = 0, hd_nx = 0, hd_kbase = 0;
  float hbm = 0.f, hbv = 0.f;

  if (is_gates) {
    mhalf = blockIdx.x >> 6;
    ngrp = blockIdx.x & 63;
    #pragma unroll
    for (int j = 0; j < 4; j++) {
      int idx = j * Hdim + ngrp * 16 + row16;  // gate j, hcol = ngrp*16+row16
      gb_bp[j] = WG + (size_t)idx * KG;
      biasv[j] = b_ih[idx] + b_hh[idx];
    }
  } else {
    int hb = blockIdx.x - 128;
    hd_mb = hb >> 3;
    hd_sb = hb & 7;
    int s = hd_sb * 16 + row16;
    hd_bpm = WMV + (size_t)s * KP;
    hd_bpv = WMV + (size_t)(128 + s) * KP;
    hbm = bm[s];
    hbv = bv[s];
    hd_kbase = w * 384;
    hd_nx = (hd_kbase < DIN) ? ((DIN - hd_kbase) >> 5) : 0;  // 12,4,0,0
    if (hd_nx > 12) hd_nx = 12;
  }

  for (int t = 0; t < Tdim; t++) {
    const int par = t & 1;
    const __hip_bfloat16* Ab = (const __hip_bfloat16*)(ws + AB_OFF + (unsigned long long)par * AB_SZ);
    __hip_bfloat16* AbW = (__hip_bfloat16*)(ws + AB_OFF + (unsigned long long)(par ^ 1) * AB_SZ);

    if (is_gates) {
      const __hip_bfloat16* aptr = Ab + (size_t)(mhalf * 64 + w * 16 + row16) * KG;
      floatx4 acc[4];
      #pragma unroll
      for (int j = 0; j < 4; j++)
        acc[j] = (floatx4){biasv[j], biasv[j], biasv[j], biasv[j]};

      // --- h-region first (K=128..1152): producers are same-mhalf gates (t)
      waitflags(flags, mhalf * 64, 63, (unsigned)t, lane);
      short8 areg[32];
      #pragma unroll
      for (int kt = 0; kt < 32; kt++)
        areg[kt] = aload16(aptr + Sdim + kt * 32 + quad * 8);  // burst: all in flight
      #pragma unroll
      for (int kt = 0; kt < 32; kt++) {
        int k0 = Sdim + kt * 32 + quad * 8;
        #pragma unroll
        for (int j = 0; j < 4; j++)
          acc[j] = MFMA(areg[kt], *(const short8*)(gb_bp[j] + k0), acc[j]);
      }
      // --- z-region (K=0..128): producers are heads blocks for my rows (t)
      waitflags(flags, 128 + mhalf * 32, 31, (unsigned)t, lane);
      short8 zreg[4];
      #pragma unroll
      for (int kt = 0; kt < 4; kt++)
        zreg[kt] = aload16(aptr + kt * 32 + quad * 8);
      #pragma unroll
      for (int kt = 0; kt < 4; kt++) {
        int k0 = kt * 32 + quad * 8;
        #pragma unroll
        for (int j = 0; j < 4; j++)
          acc[j] = MFMA(zreg[kt], *(const short8*)(gb_bp[j] + k0), acc[j]);
      }
      // --- LSTM cell, fully lane-local: acc[j][r] = gate j at (row quad*4+r, hcol row16)
      int hc = ngrp * 16 + row16;
      #pragma unroll
      for (int r = 0; r < 4; r++) {
        float cn = sigf(acc[1][r]) * creg[r] + sigf(acc[0][r]) * tanhfast(acc[2][r]);
        creg[r] = cn;
        float hn = sigf(acc[3][r]) * tanhfast(cn);
        __hip_bfloat16 hbf = __float2bfloat16(hn);
        unsigned hu = (unsigned)reinterpret_cast<unsigned short&>(hbf);
        unsigned other = __shfl_xor(hu, 1, 64);  // neighbor hcol (row16^1)
        if ((row16 & 1) == 0) {
          int grow = mhalf * 64 + w * 16 + quad * 4 + r;
          astore4(AbW + (size_t)grow * KG + Sdim + hc, hu | (other << 16));
        }
      }
      __syncthreads();  // drain all waves' h-stores (vmcnt 0) before publishing
      if (tid == 0)
        __hip_atomic_store(&flags[blockIdx.x], (unsigned)(t + 1),
                           __ATOMIC_RELAXED, __HIP_MEMORY_SCOPE_AGENT);
    } else {
      // --- x-region first (static input, no wait)
      const __hip_bfloat16* axp = xbf + ((size_t)(hd_mb * 16 + row16) * Tdim + t) * DIN;
      const __hip_bfloat16* ahp = AbW + (size_t)(hd_mb * 16 + row16) * KG + Sdim;
      floatx4 am, av;
      if (w == 0) { am = (floatx4){hbm, hbm, hbm, hbm}; av = (floatx4){hbv, hbv, hbv, hbv}; }
      else        { am = (floatx4){0.f, 0.f, 0.f, 0.f}; av = (floatx4){0.f, 0.f, 0.f, 0.f}; }
      #pragma unroll
      for (int kt = 0; kt < 12; kt++) {
        if (kt < hd_nx) {
          int k0 = hd_kbase + kt * 32 + quad * 8;
          short8 a = *(const short8*)(axp + k0);
          am = MFMA(a, *(const short8*)(hd_bpm + k0), am);
          av = MFMA(a, *(const short8*)(hd_bpv + k0), av);
        }
      }
      // --- h-region: wait for the 64 gates blocks covering my rows to finish step t
      waitflags(flags, (hd_mb >> 2) * 64, 63, (unsigned)(t + 1), lane);
      short8 hreg[12];
      #pragma unroll
      for (int kt = 0; kt < 12; kt++) {
        if (kt >= hd_nx)
          hreg[kt] = aload16(ahp + hd_kbase + kt * 32 + quad * 8 - DIN);
      }
      #pragma unroll
      for (int kt = 0; kt < 12; kt++) {
        if (kt >= hd_nx) {
          int k0 = hd_kbase + kt * 32 + quad * 8;
          am = MFMA(hreg[kt], *(const short8*)(hd_bpm + k0), am);
          av = MFMA(hreg[kt], *(const short8*)(hd_bpv + k0), av);
        }
      }
      // --- cross-wave K reduction through LDS
      #pragma unroll
      for (int r = 0; r < 4; r++) {
        smem[(w * 2 + 0) * 256 + lane * 4 + r] = am[r];
        smem[(w * 2 + 1) * 256 + lane * 4 + r] = av[r];
      }
      __syncthreads();
      if (w == 0) {
        float kls = 0.0f;
        #pragma unroll
        for (int r = 0; r < 4; r++) {
          int idx = lane * 4 + r;
          float mean = smem[0 * 256 + idx] + smem[2 * 256 + idx] +
                       smem[4 * 256 + idx] + smem[6 * 256 + idx];
          float lv = smem[1 * 256 + idx] + smem[3 * 256 + idx] +
                     smem[5 * 256 + idx] + smem[7 * 256 + idx];
          int b = hd_mb * 16 + quad * 4 + r;
          int s = hd_sb * 16 + row16;
          float std = __expf(0.5f * lv);
          float nt = noise[((size_t)b * Tdim + t) * Sdim + s];
          float z = nt * std + mean;
          __hip_bfloat16 zb = __float2bfloat16(z);
          zall[((size_t)b * Tdim + t) * Sdim + s] = zb;  // scan-private: normal store
          float zo = __shfl_xor(z, 1, 64);
          if ((row16 & 1) == 0) {
            __hip_bfloat16 zb2 = __float2bfloat16(zo);
            unsigned lo = reinterpret_cast<unsigned short&>(zb);
            unsigned hi = reinterpret_cast<unsigned short&>(zb2);
            astore4(AbW + (size_t)b * KG + s, lo | (hi << 16));
          }
          kls += std * std + mean * mean - 0.5f * lv - 0.5f;  // log(std)=0.5*lv
        }
        #pragma unroll
        for (int off = 32; off > 0; off >>= 1) kls += __shfl_down(kls, off, 64);
        if (lane == 0) atomicAdd(klacc, kls);
      }
      __syncthreads();  // w0's z-stores drained before publish
      if (tid == 0)
        __hip_atomic_store(&flags[blockIdx.x], (unsigned)(t + 1),
                           __ATOMIC_RELAXED, __HIP_MEMORY_SCOPE_AGENT);
    }
  }
}

// ---------------- decoder GEMM1: Hbuf = relu(zall[32768,128] @ Wd1^T + bd1) -> bf16
__global__ __launch_bounds__(256) void dec1_kernel(char* __restrict__ ws,
                                                   const float* __restrict__ bd1) {
  const __hip_bfloat16* zall = (const __hip_bfloat16*)(ws + ZALL_OFF);
  const __hip_bfloat16* Wd1b = (const __hip_bfloat16*)(ws + WD1_OFF);
  __hip_bfloat16* Hbuf = (__hip_bfloat16*)(ws + HB_OFF);
  int tid = threadIdx.x, lane = tid & 63, w = tid >> 6;
  int mb = blockIdx.x, nb = blockIdx.y;
  int row16 = lane & 15, quad = lane >> 4;
  int arow = mb * 64 + w * 16 + row16;
  const __hip_bfloat16* aptr = zall + (size_t)arow * Sdim;
  floatx4 acc[4] = {{0.f,0.f,0.f,0.f},{0.f,0.f,0.f,0.f},{0.f,0.f,0.f,0.f},{0.f,0.f,0.f,0.f}};
  #pragma unroll
  for (int kt = 0; kt < Sdim / 32; kt++) {
    int k0 = kt * 32 + quad * 8;
    short8 a = *(const short8*)(aptr + k0);
    #pragma unroll
    for (int j = 0; j < 4; j++) {
      const __hip_bfloat16* bp = Wd1b + (size_t)(nb * 64 + j * 16 + row16) * Sdim;
      acc[j] = MFMA(a, *(const short8*)(bp + k0), acc[j]);
    }
  }
  #pragma unroll
  for (int j = 0; j < 4; j++) {
    int n = nb * 64 + j * 16 + row16;
    float bias = bd1[n];
    #pragma unroll
    for (int r = 0; r < 4; r++) {
      int rr = mb * 64 + w * 16 + quad * 4 + r;
      float v = fmaxf(acc[j][r] + bias, 0.0f);
      Hbuf[(size_t)rr * DHdim + n] = __float2bfloat16(v);
    }
  }
}

// ---------------- decoder GEMM2: out = Hbuf[32768,1024] @ Wd2^T + bd2 -> f32
__global__ __launch_bounds__(256) void dec2_kernel(char* __restrict__ ws,
                                                   const float* __restrict__ bd2,
                                                   float* __restrict__ out) {
  const __hip_bfloat16* Hbuf = (const __hip_bfloat16*)(ws + HB_OFF);
  const __hip_bfloat16* Wd2b = (const __hip_bfloat16*)(ws + WD2_OFF);
  int tid = threadIdx.x, lane = tid & 63, w = tid >> 6;
  int mb = blockIdx.x, nb = blockIdx.y;
  int row16 = lane & 15, quad = lane >> 4;
  int arow = mb * 64 + w * 16 + row16;
  const __hip_bfloat16* aptr = Hbuf + (size_t)arow * DHdim;
  const __hip_bfloat16* bp[4];
  #pragma unroll
  for (int j = 0; j < 4; j++) bp[j] = Wd2b + (size_t)(nb * 64 + j * 16 + row16) * DHdim;
  floatx4 acc[4] = {{0.f,0.f,0.f,0.f},{0.f,0.f,0.f,0.f},{0.f,0.f,0.f,0.f},{0.f,0.f,0.f,0.f}};
  for (int kt = 0; kt < DHdim / 32; kt++) {
    int k0 = kt * 32 + quad * 8;
    short8 a = *(const short8*)(aptr + k0);
    #pragma unroll
    for (int j = 0; j < 4; j++)
      acc[j] = MFMA(a, *(const short8*)(bp[j] + k0), acc[j]);
  }
  #pragma unroll
  for (int j = 0; j < 4; j++) {
    int n = nb * 64 + j * 16 + row16;
    float bias = bd2[n];
    #pragma unroll
    for (int r = 0; r < 4; r++) {
      int rr = mb * 64 + w * 16 + quad * 4 + r;
      out[(size_t)rr * DIN + n] = acc[j][r] + bias;
    }
  }
}

__global__ void kl_write_kernel(const char* __restrict__ ws, float* __restrict__ out) {
  if (threadIdx.x == 0 && blockIdx.x == 0)
    out[16777216] = *(const float*)(ws + KL_OFF);
}

extern "C" void kernel_launch(void* const* d_in, const int* in_sizes, int n_in,
                              void* d_out, int out_size, void* d_ws, size_t ws_size,
                              hipStream_t stream) {
  const float* x = (const float*)d_in[0];
  const float* noise = (const float*)d_in[1];
  const float* W_ih = (const float*)d_in[2];
  const float* W_hh = (const float*)d_in[3];
  const float* b_ih = (const float*)d_in[4];
  const float* b_hh = (const float*)d_in[5];
  const float* Wm = (const float*)d_in[6];
  const float* bm = (const float*)d_in[7];
  const float* Wv = (const float*)d_in[8];
  const float* bv = (const float*)d_in[9];
  const float* Wd1 = (const float*)d_in[10];
  const float* bd1 = (const float*)d_in[11];
  const float* Wd2 = (const float*)d_in[12];
  const float* bd2 = (const float*)d_in[13];
  char* ws = (char*)d_ws;
  float* out = (float*)d_out;

  long long total_prep = 22692033LL;
  int pblocks = (int)((total_prep + 255) / 256);
  prep_kernel<<<pblocks, 256, 0, stream>>>(x, W_ih, W_hh, Wm, Wv, Wd1, Wd2, ws);
  scan_kernel<<<NBLK, 256, 0, stream>>>(ws, noise, b_ih, b_hh, bm, bv);
  dec1_kernel<<<dim3(512, 16), 256, 0, stream>>>(ws, bd1);
  dec2_kernel<<<dim3(512, 8), 256, 0, stream>>>(ws, bd2, out);
  kl_write_kernel<<<1, 64, 0, stream>>>(ws, out);
}